// Round 1
// baseline (657.995 us; speedup 1.0000x reference)
//
#include <hip/hip_runtime.h>

// NCC loss, win=9, volume (1,1,160,192,224) fp32 -> scalar.
// Separable 9-tap box sums over 5 channels (I, J, I2, J2, IJ):
//   pass_w: reads I,J, forms products on the fly, sums along W  -> bufA (chunked in D)
//   pass_h: sums along H                                        -> bufB (full volume)
//   pass_d_reduce: sums along D, computes cc, block-reduces, atomicAdd -> d_out
// Chunking the W/H passes along D (CHUNK=40) keeps workspace at
// 5*NVOX + 5*CHUNK*SLICE floats = 172 MB.

#define DD 160
#define HH 192
#define WW 224
#define SLICE (HH * WW)          // 43008
#define NVOX (DD * SLICE)        // 6881280
#define RAD 4
#define CHUNK 40
#define WSUM 729.0f
#define EPS 1e-5f

__global__ __launch_bounds__(256) void pass_w(const float* __restrict__ I,
                                              const float* __restrict__ J,
                                              float* __restrict__ out, int d0) {
    int w  = blockIdx.x * 64 + threadIdx.x;
    int h  = blockIdx.y * 4 + threadIdx.y;
    int dz = blockIdx.z;                 // local slice index within chunk
    if (w >= WW) return;
    int d = d0 + dz;
    const float* Ir = I + (size_t)d * SLICE + (size_t)h * WW;
    const float* Jr = J + (size_t)d * SLICE + (size_t)h * WW;
    int lo = w - RAD; if (lo < 0) lo = 0;
    int hi = w + RAD; if (hi > WW - 1) hi = WW - 1;
    float sI = 0.f, sJ = 0.f, sI2 = 0.f, sJ2 = 0.f, sIJ = 0.f;
    for (int x = lo; x <= hi; ++x) {
        float a = Ir[x], b = Jr[x];
        sI += a; sJ += b; sI2 += a * a; sJ2 += b * b; sIJ += a * b;
    }
    const size_t F = (size_t)CHUNK * SLICE;
    size_t idx = (size_t)dz * SLICE + (size_t)h * WW + w;
    out[idx]         = sI;
    out[F + idx]     = sJ;
    out[2 * F + idx] = sI2;
    out[3 * F + idx] = sJ2;
    out[4 * F + idx] = sIJ;
}

__global__ __launch_bounds__(256) void pass_h(const float* __restrict__ in,
                                              float* __restrict__ out, int d0) {
    int w  = blockIdx.x * 64 + threadIdx.x;
    int h  = blockIdx.y * 4 + threadIdx.y;
    int dz = blockIdx.z;
    if (w >= WW) return;
    const size_t F = (size_t)CHUNK * SLICE;
    int lo = h - RAD; if (lo < 0) lo = 0;
    int hi = h + RAD; if (hi > HH - 1) hi = HH - 1;
    const float* base = in + (size_t)dz * SLICE + w;
    float s0 = 0.f, s1 = 0.f, s2 = 0.f, s3 = 0.f, s4 = 0.f;
    for (int y = lo; y <= hi; ++y) {
        size_t j = (size_t)y * WW;
        s0 += base[j];
        s1 += base[F + j];
        s2 += base[2 * F + j];
        s3 += base[3 * F + j];
        s4 += base[4 * F + j];
    }
    size_t idx = (size_t)(d0 + dz) * SLICE + (size_t)h * WW + w;
    out[idx]                   = s0;
    out[(size_t)NVOX + idx]    = s1;
    out[2 * (size_t)NVOX + idx] = s2;
    out[3 * (size_t)NVOX + idx] = s3;
    out[4 * (size_t)NVOX + idx] = s4;
}

__global__ __launch_bounds__(256) void pass_d_reduce(const float* __restrict__ in,
                                                     float* __restrict__ out) {
    int w = blockIdx.x * 64 + threadIdx.x;
    int h = blockIdx.y * 4 + threadIdx.y;
    int d = blockIdx.z;
    float cc = 0.f;
    if (w < WW) {
        int lo = d - RAD; if (lo < 0) lo = 0;
        int hi = d + RAD; if (hi > DD - 1) hi = DD - 1;
        const float* base = in + (size_t)h * WW + w;
        float s0 = 0.f, s1 = 0.f, s2 = 0.f, s3 = 0.f, s4 = 0.f;
        for (int z = lo; z <= hi; ++z) {
            size_t j = (size_t)z * SLICE;
            s0 += base[j];
            s1 += base[(size_t)NVOX + j];
            s2 += base[2 * (size_t)NVOX + j];
            s3 += base[3 * (size_t)NVOX + j];
            s4 += base[4 * (size_t)NVOX + j];
        }
        const float inv = 1.0f / WSUM;
        float cross = s4 - s0 * s1 * inv;
        float iv    = s2 - s0 * s0 * inv;
        float jv    = s3 - s1 * s1 * inv;
        cc = cross * cross / (iv * jv + EPS);
    }
    // wave (64-lane) reduction, then cross-wave via LDS. blockDim=(64,4,1):
    // lane = threadIdx.x, wave id = threadIdx.y.
    for (int off = 32; off > 0; off >>= 1)
        cc += __shfl_down(cc, off, 64);
    __shared__ float wsum[4];
    if (threadIdx.x == 0) wsum[threadIdx.y] = cc;
    __syncthreads();
    if (threadIdx.x == 0 && threadIdx.y == 0) {
        float t = wsum[0] + wsum[1] + wsum[2] + wsum[3];
        atomicAdd(out, t * (-1.0f / (float)NVOX));
    }
}

extern "C" void kernel_launch(void* const* d_in, const int* in_sizes, int n_in,
                              void* d_out, int out_size, void* d_ws, size_t ws_size,
                              hipStream_t stream) {
    const float* I = (const float*)d_in[0];
    const float* J = (const float*)d_in[1];
    float* out  = (float*)d_out;
    float* bufB = (float*)d_ws;                         // 5*NVOX floats (137.6 MB)
    float* bufA = bufB + 5 * (size_t)NVOX;              // 5*CHUNK*SLICE floats (34.4 MB)

    hipMemsetAsync(d_out, 0, sizeof(float), stream);    // harness re-poisons d_out

    dim3 blk(64, 4, 1);
    dim3 grdC((WW + 63) / 64, HH / 4, CHUNK);
    for (int d0 = 0; d0 < DD; d0 += CHUNK) {
        pass_w<<<grdC, blk, 0, stream>>>(I, J, bufA, d0);
        pass_h<<<grdC, blk, 0, stream>>>(bufA, bufB, d0);
    }
    dim3 grdF((WW + 63) / 64, HH / 4, DD);
    pass_d_reduce<<<grdF, blk, 0, stream>>>(bufB, out);
}

// Round 2
// 193.387 us; speedup vs baseline: 3.4025x; 3.4025x over previous
//
#include <hip/hip_runtime.h>

// NCC loss, win=9, (1,1,160,192,224) fp32 -> scalar. FULLY FUSED single kernel.
// Block = 32x16 (W,H) output tile, marching D in a chunk of 20 slices (+8 halo).
// Per slice: global->LDS haloed tile (40x24) of I,J; 9-tap W-sum of the 5
// products (I,J,I2,J2,IJ) -> LDS; 9-tap H-sum -> 5 regs; 9-deep register
// shift-queue gives the sliding D-window sum (zero-pad handled by zero halos
// and zero-initialized queue). cc epilogue fused, hierarchical reduction,
// one atomicAdd per block. Intermediate global traffic: ZERO.

#define DD 160
#define HH 192
#define WW 224
#define SLICE (HH * WW)
#define NVOX (DD * SLICE)
#define TW 32
#define TH 16
#define EXTW (TW + 8)            // 40
#define EXTH (TH + 8)            // 24
#define DCH 20                   // D-slices per block -> grid.z = 8
#define NPOS (EXTH * TW)         // 768 W-sum positions per slice
#define NTHR (TW * TH)           // 512 threads
#define EPS 1e-5f
#define INV_WSUM (1.0f / 729.0f)

__global__ __launch_bounds__(NTHR) void ncc_fused(const float* __restrict__ I,
                                                  const float* __restrict__ J,
                                                  float* __restrict__ out) {
    __shared__ float sI[EXTH][EXTW];
    __shared__ float sJ[EXTH][EXTW];
    __shared__ float SW[5][EXTH][TW];   // W-summed products
    __shared__ float wred[NTHR / 64];

    const int tx = threadIdx.x, ty = threadIdx.y;
    const int tid = ty * TW + tx;
    const int wlo = blockIdx.x * TW;
    const int hlo = blockIdx.y * TH;
    const int dlo = blockIdx.z * DCH;

    // 9-deep shift queue of WH-sums (5 channels), all-static indexing.
    float q0[9], q1[9], q2[9], q3[9], q4[9];
    #pragma unroll
    for (int k = 0; k < 9; ++k) { q0[k]=0.f; q1[k]=0.f; q2[k]=0.f; q3[k]=0.f; q4[k]=0.f; }
    float r0=0.f, r1=0.f, r2=0.f, r3=0.f, r4=0.f;   // running D-window sums
    float acc = 0.f;                                 // cc accumulator

    for (int i = 0; i < DCH + 8; ++i) {
        const int z = dlo - 4 + i;
        const bool valid = (z >= 0) && (z < DD);

        if (valid) {
            for (int e = tid; e < EXTH * EXTW; e += NTHR) {
                int r = e / EXTW, c = e % EXTW;
                int gh = hlo - 4 + r, gw = wlo - 4 + c;
                float a = 0.f, b = 0.f;
                if (gh >= 0 && gh < HH && gw >= 0 && gw < WW) {
                    size_t g = (size_t)z * SLICE + (size_t)gh * WW + gw;
                    a = I[g]; b = J[g];
                }
                sI[r][c] = a; sJ[r][c] = b;
            }
        }
        __syncthreads();

        if (valid) {
            for (int p = tid; p < NPOS; p += NTHR) {
                int r = p >> 5, c = p & (TW - 1);
                float s0=0.f, s1=0.f, s2=0.f, s3=0.f, s4=0.f;
                #pragma unroll
                for (int k = 0; k < 9; ++k) {
                    float a = sI[r][c + k], b = sJ[r][c + k];
                    s0 += a; s1 += b; s2 += a * a; s3 += b * b; s4 += a * b;
                }
                SW[0][r][c] = s0; SW[1][r][c] = s1; SW[2][r][c] = s2;
                SW[3][r][c] = s3; SW[4][r][c] = s4;
            }
        }
        __syncthreads();

        float w0=0.f, w1=0.f, w2=0.f, w3=0.f, w4=0.f;
        if (valid) {
            #pragma unroll
            for (int k = 0; k < 9; ++k) {
                w0 += SW[0][ty + k][tx];
                w1 += SW[1][ty + k][tx];
                w2 += SW[2][ty + k][tx];
                w3 += SW[3][ty + k][tx];
                w4 += SW[4][ty + k][tx];
            }
        }

        // slide the D window: add newest (z = d_out+4), drop z = d_out-5
        r0 += w0 - q0[0]; r1 += w1 - q1[0]; r2 += w2 - q2[0];
        r3 += w3 - q3[0]; r4 += w4 - q4[0];
        #pragma unroll
        for (int k = 0; k < 8; ++k) {
            q0[k]=q0[k+1]; q1[k]=q1[k+1]; q2[k]=q2[k+1]; q3[k]=q3[k+1]; q4[k]=q4[k+1];
        }
        q0[8]=w0; q1[8]=w1; q2[8]=w2; q3[8]=w3; q4[8]=w4;

        if (i >= 8) {   // emit d_out = dlo + i - 8
            float cross = r4 - r0 * r1 * INV_WSUM;
            float iv    = r2 - r0 * r0 * INV_WSUM;
            float jv    = r3 - r1 * r1 * INV_WSUM;
            acc += cross * cross / (iv * jv + EPS);
        }
    }

    // hierarchical reduction: wave64 shuffle -> LDS -> one atomic per block
    #pragma unroll
    for (int off = 32; off > 0; off >>= 1) acc += __shfl_down(acc, off, 64);
    if ((tid & 63) == 0) wred[tid >> 6] = acc;
    __syncthreads();
    if (tid == 0) {
        float t = 0.f;
        #pragma unroll
        for (int k = 0; k < NTHR / 64; ++k) t += wred[k];
        atomicAdd(out, t * (-1.0f / (float)NVOX));
    }
}

extern "C" void kernel_launch(void* const* d_in, const int* in_sizes, int n_in,
                              void* d_out, int out_size, void* d_ws, size_t ws_size,
                              hipStream_t stream) {
    const float* I = (const float*)d_in[0];
    const float* J = (const float*)d_in[1];
    float* out = (float*)d_out;

    hipMemsetAsync(d_out, 0, sizeof(float), stream);  // harness re-poisons d_out

    dim3 blk(TW, TH, 1);
    dim3 grd(WW / TW, HH / TH, DD / DCH);             // 7 x 12 x 8 = 672 blocks
    ncc_fused<<<grd, blk, 0, stream>>>(I, J, out);
}

// Round 3
// 164.141 us; speedup vs baseline: 4.0087x; 1.1782x over previous
//
#include <hip/hip_runtime.h>

// NCC loss, win=9, (1,1,160,192,224) fp32 -> scalar. Fully fused, round 3.
// Block = 512 threads, output tile TW=32 x TH=16, marching D in DCH=10 slices
// (18 slice-iters = 2 x 9 -> static-phase ring queue, no register shifting).
// Per slice: f4 global->LDS stage (left halo 8 for 16B alignment), f4 sliding-
// window W-sums (threads 0..191), scalar 9-tap H-sum, O(1) D-window update,
// fused cc epilogue + reduction. 2 barriers/slice, single-buffered (safe:
// sI rewrite and SW rewrite are each separated from their readers by the two
// barriers of the iteration boundary).

#define DD 160
#define HH 192
#define WW 224
#define SLICE (HH * WW)
#define NVOX (DD * SLICE)
#define TW 32
#define TH 16
#define EXTH (TH + 8)            // 24 rows (H halo 4+4)
#define EXTW4 12                 // 48 floats/row: halo 8 left + 8 right, f4-aligned
#define DCH 10                   // grid.z = 16, iters = 18 = 2*9
#define NTHR 512
#define NSTG (2 * EXTH * EXTW4)  // 576 f4 staging elements (sI + sJ)
#define WPOS (EXTH * (TW / 4))   // 192 f4 W-sum positions
#define EPS 1e-5f
#define INV_WSUM (1.0f / 729.0f)

__global__ __launch_bounds__(NTHR, 4) void ncc_fused(const float* __restrict__ I,
                                                     const float* __restrict__ J,
                                                     float* __restrict__ out) {
    __shared__ float4 sIv[EXTH][EXTW4];
    __shared__ float4 sJv[EXTH][EXTW4];
    __shared__ float4 SWv[5][EXTH][TW / 4];   // W-summed products, f4 along W
    __shared__ float wred[NTHR / 64];

    const float* SWs = (const float*)SWv;     // scalar view: [ch*768 + row*32 + col]

    const int tid = threadIdx.x;
    const int tx = tid & 31;          // W column within tile
    const int ty = tid >> 5;          // H row within tile, [0,16)
    const int wlo = blockIdx.x * TW;
    const int hlo = blockIdx.y * TH;
    const int dlo = blockIdx.z * DCH;

    const float4* Iv = (const float4*)I;
    const float4* Jv = (const float4*)J;

    float q0[9], q1[9], q2[9], q3[9], q4[9];
    #pragma unroll
    for (int k = 0; k < 9; ++k) { q0[k]=0.f; q1[k]=0.f; q2[k]=0.f; q3[k]=0.f; q4[k]=0.f; }
    float r0=0.f, r1=0.f, r2=0.f, r3=0.f, r4=0.f;
    float acc = 0.f;

    for (int g = 0; g < 2; ++g) {
        #pragma unroll
        for (int ph = 0; ph < 9; ++ph) {
            const int i = g * 9 + ph;
            const int z = dlo - 4 + i;
            const bool valid = (z >= 0) && (z < DD);   // block-uniform

            // ---- stage: global -> LDS, float4, zero-filled halo ----
            if (valid) {
                const int zbase = z * (SLICE / 4);
                auto stage_one = [&](int e) {
                    bool isJ = e >= (NSTG / 2);
                    int a = isJ ? e - (NSTG / 2) : e;
                    int r = a / EXTW4, c = a - r * EXTW4;
                    int gh = hlo - 4 + r;
                    int gf = (wlo >> 2) - 2 + c;       // global f4 column
                    float4 v = make_float4(0.f, 0.f, 0.f, 0.f);
                    if (gh >= 0 && gh < HH && gf >= 0 && gf < (WW / 4)) {
                        const float4* src = isJ ? Jv : Iv;
                        v = src[zbase + gh * (WW / 4) + gf];
                    }
                    float4* dst = isJ ? &sJv[0][0] : &sIv[0][0];
                    dst[a] = v;
                };
                stage_one(tid);
                if (tid < NSTG - NTHR) stage_one(tid + NTHR);
            }
            __syncthreads();

            // ---- W-stage: sliding 9-tap sums of 5 products, f4 outputs ----
            if (valid && tid < WPOS) {
                int r = tid >> 3, c = tid & 7;
                float4 a0 = sIv[r][c + 1], a1 = sIv[r][c + 2],
                       a2 = sIv[r][c + 3], a3 = sIv[r][c + 4];
                float4 b0 = sJv[r][c + 1], b1 = sJv[r][c + 2],
                       b2 = sJv[r][c + 3], b3 = sJv[r][c + 4];
                float ax[12] = {a0.x,a0.y,a0.z,a0.w, a1.x,a1.y,a1.z,a1.w,
                                a2.x,a2.y,a2.z,a2.w};
                float bx[12] = {b0.x,b0.y,b0.z,b0.w, b1.x,b1.y,b1.z,b1.w,
                                b2.x,b2.y,b2.z,b2.w};
                // channel 0: I ; 1: J ; 2: I2 ; 3: J2 ; 4: IJ
                #pragma unroll
                for (int ch = 0; ch < 5; ++ch) {
                    float v[12];
                    #pragma unroll
                    for (int k = 0; k < 12; ++k) {
                        float e = (ch == 0) ? ax[k]
                                : (ch == 1) ? bx[k]
                                : (ch == 2) ? ax[k] * ax[k]
                                : (ch == 3) ? bx[k] * bx[k]
                                :             ax[k] * bx[k];
                        v[k] = e;
                    }
                    float s = v[0];
                    #pragma unroll
                    for (int k = 1; k < 9; ++k) s += v[k];
                    float4 o;
                    o.x = s;
                    s += v[9]  - v[0]; o.y = s;
                    s += v[10] - v[1]; o.z = s;
                    s += v[11] - v[2]; o.w = s;
                    SWv[ch][r][c] = o;
                }
            }
            __syncthreads();

            // ---- H-stage: 9-tap over SW columns ----
            float w0=0.f, w1=0.f, w2=0.f, w3=0.f, w4=0.f;
            if (valid) {
                const float* p = SWs + ty * TW + tx;
                #pragma unroll
                for (int k = 0; k < 9; ++k) {
                    int j = k * TW;
                    w0 += p[j];
                    w1 += p[768 + j];
                    w2 += p[1536 + j];
                    w3 += p[2304 + j];
                    w4 += p[3072 + j];
                }
            }

            // ---- O(1) D-window update (static phase index) ----
            r0 += w0 - q0[ph]; q0[ph] = w0;
            r1 += w1 - q1[ph]; q1[ph] = w1;
            r2 += w2 - q2[ph]; q2[ph] = w2;
            r3 += w3 - q3[ph]; q3[ph] = w3;
            r4 += w4 - q4[ph]; q4[ph] = w4;

            if (i >= 8) {
                float cross = r4 - r0 * r1 * INV_WSUM;
                float iv    = r2 - r0 * r0 * INV_WSUM;
                float jv    = r3 - r1 * r1 * INV_WSUM;
                acc += cross * cross * __builtin_amdgcn_rcpf(iv * jv + EPS);
            }
        }
    }

    // ---- block reduction -> one atomic ----
    #pragma unroll
    for (int off = 32; off > 0; off >>= 1) acc += __shfl_down(acc, off, 64);
    if ((tid & 63) == 0) wred[tid >> 6] = acc;
    __syncthreads();
    if (tid == 0) {
        float t = 0.f;
        #pragma unroll
        for (int k = 0; k < NTHR / 64; ++k) t += wred[k];
        atomicAdd(out, t * (-1.0f / (float)NVOX));
    }
}

extern "C" void kernel_launch(void* const* d_in, const int* in_sizes, int n_in,
                              void* d_out, int out_size, void* d_ws, size_t ws_size,
                              hipStream_t stream) {
    const float* I = (const float*)d_in[0];
    const float* J = (const float*)d_in[1];
    float* out = (float*)d_out;

    hipMemsetAsync(d_out, 0, sizeof(float), stream);  // harness re-poisons d_out

    dim3 blk(NTHR, 1, 1);
    dim3 grd(WW / TW, HH / TH, DD / DCH);             // 7 x 12 x 16 = 1344 blocks
    ncc_fused<<<grd, blk, 0, stream>>>(I, J, out);
}

// Round 4
// 148.398 us; speedup vs baseline: 4.4340x; 1.1061x over previous
//
#include <hip/hip_runtime.h>

// NCC loss, win=9, (1,1,160,192,224) fp32 -> scalar. Fully fused, round 4.
// 512 threads, tile TW=32 x TH=16, marching D with DCH=10 (18 iters = 2x9,
// static-phase ring queue). Per slice:
//   W-stage (192 thr): direct global float4 loads (no LDS staging), products,
//                      sliding 9-tap W-sums -> SW (b32 writes, stride-33 rows)
//   H-stage (160 thr): per-(ch,col) 24-row column slide -> 16 H-sums -> SH
//   F-stage (512 thr): 5 b32 reads, O(1) D-ring update, fused cc epilogue.
// 2 barriers/slice, single-buffered (barB separates H(i) SW-reads from
// W(i+1) SW-writes; barA separates F(i) SH-reads from H(i+1) SH-writes).
// All LDS patterns <=2-way bank aliasing (free on CDNA4).

#define DD 160
#define HH 192
#define WW 224
#define W4 56                 // WW/4
#define SLICE (HH * WW)
#define NVOX (DD * SLICE)
#define TW 32
#define TH 16
#define EXTH 24
#define DCH 10                // grid.z = 16
#define NTHR 512
#define SW_RS 33              // odd row stride -> conflict-free columns
#define SW_CS (EXTH * SW_RS)  // 792
#define SH_RS 33
#define SH_CS (TH * SH_RS)    // 528
#define EPS 1e-5f
#define INV_WSUM (1.0f / 729.0f)

__global__ __launch_bounds__(NTHR, 4) void ncc_fused(const float* __restrict__ I,
                                                     const float* __restrict__ J,
                                                     float* __restrict__ out) {
    __shared__ float SW[5 * SW_CS];   // 15.8 KB
    __shared__ float SH[5 * SH_CS];   // 10.6 KB
    __shared__ float wred[NTHR / 64];

    const int tid = threadIdx.x;
    const int tx = tid & 31, ty = tid >> 5;
    const int wlo = blockIdx.x * TW;
    const int hlo = blockIdx.y * TH;
    const int dlo = blockIdx.z * DCH;

    // W-stage ids (tid < 192): 24 rows x 8 f4-cols
    const int wr = tid >> 3;
    const int wc = tid & 7;
    const int gh = hlo - 4 + wr;
    const bool hok = (gh >= 0) && (gh < HH);
    const int gf0 = (wlo >> 2) - 1 + wc;

    // H-stage ids (tid < 160): 5 channels x 32 cols
    const int hcol = tid & 31;
    const int hch = tid >> 5;

    const float4* Iv = (const float4*)I;
    const float4* Jv = (const float4*)J;

    float q0[9], q1[9], q2[9], q3[9], q4[9];
    #pragma unroll
    for (int k = 0; k < 9; ++k) { q0[k]=0.f; q1[k]=0.f; q2[k]=0.f; q3[k]=0.f; q4[k]=0.f; }
    float r0=0.f, r1=0.f, r2=0.f, r3=0.f, r4=0.f;
    float acc = 0.f;

    #pragma unroll 1
    for (int g = 0; g < 2; ++g) {
        #pragma unroll
        for (int ph = 0; ph < 9; ++ph) {
            const int i = g * 9 + ph;
            const int z = dlo - 4 + i;
            const bool valid = (z >= 0) && (z < DD);   // block-uniform

            // ---- W-stage: direct-global loads + sliding W-sums -> SW ----
            if (valid && tid < 192) {
                const int rowb = z * (SLICE / 4) + gh * W4;
                float ax[12], bx[12];
                #pragma unroll
                for (int k = 0; k < 3; ++k) {
                    const int f = gf0 + k;
                    float4 a = make_float4(0.f, 0.f, 0.f, 0.f);
                    float4 b = make_float4(0.f, 0.f, 0.f, 0.f);
                    if (hok && f >= 0 && f < W4) { a = Iv[rowb + f]; b = Jv[rowb + f]; }
                    ax[4*k] = a.x; ax[4*k+1] = a.y; ax[4*k+2] = a.z; ax[4*k+3] = a.w;
                    bx[4*k] = b.x; bx[4*k+1] = b.y; bx[4*k+2] = b.z; bx[4*k+3] = b.w;
                }
                float p2[12], p3[12], p4[12];
                #pragma unroll
                for (int k = 0; k < 12; ++k) {
                    p2[k] = ax[k] * ax[k];
                    p3[k] = bx[k] * bx[k];
                    p4[k] = ax[k] * bx[k];
                }
                float* wp = SW + wr * SW_RS + 4 * wc;
                auto emitch = [&](const float* v, float* o) {
                    float s = v[0];
                    #pragma unroll
                    for (int k = 1; k < 9; ++k) s += v[k];
                    o[0] = s;
                    s += v[9]  - v[0]; o[1] = s;
                    s += v[10] - v[1]; o[2] = s;
                    s += v[11] - v[2]; o[3] = s;
                };
                emitch(ax, wp);
                emitch(bx, wp + SW_CS);
                emitch(p2, wp + 2 * SW_CS);
                emitch(p3, wp + 3 * SW_CS);
                emitch(p4, wp + 4 * SW_CS);
            }
            __syncthreads();   // barA: SW visible; SH safe to rewrite

            // ---- H-stage: per-(ch,col) column slide -> SH ----
            if (valid && tid < 160) {
                const float* p = SW + hch * SW_CS + hcol;
                float v[24];
                #pragma unroll
                for (int r = 0; r < 24; ++r) v[r] = p[r * SW_RS];
                float s = v[0];
                #pragma unroll
                for (int r = 1; r < 9; ++r) s += v[r];
                float* o = SH + hch * SH_CS + hcol;
                o[0] = s;
                #pragma unroll
                for (int r = 1; r < 16; ++r) {
                    s += v[r + 8] - v[r - 1];
                    o[r * SH_RS] = s;
                }
            }
            __syncthreads();   // barB: SH visible; SW safe to rewrite

            // ---- F-stage: read 5 ch, D-ring update, cc ----
            float w0=0.f, w1=0.f, w2=0.f, w3=0.f, w4=0.f;
            if (valid) {
                const float* p = SH + ty * SH_RS + tx;
                w0 = p[0];
                w1 = p[SH_CS];
                w2 = p[2 * SH_CS];
                w3 = p[3 * SH_CS];
                w4 = p[4 * SH_CS];
            }
            r0 += w0 - q0[ph]; q0[ph] = w0;
            r1 += w1 - q1[ph]; q1[ph] = w1;
            r2 += w2 - q2[ph]; q2[ph] = w2;
            r3 += w3 - q3[ph]; q3[ph] = w3;
            r4 += w4 - q4[ph]; q4[ph] = w4;

            if (i >= 8) {
                float cross = r4 - r0 * r1 * INV_WSUM;
                float iv    = r2 - r0 * r0 * INV_WSUM;
                float jv    = r3 - r1 * r1 * INV_WSUM;
                acc += cross * cross * __builtin_amdgcn_rcpf(iv * jv + EPS);
            }
        }
    }

    // ---- block reduction -> one atomic ----
    #pragma unroll
    for (int off = 32; off > 0; off >>= 1) acc += __shfl_down(acc, off, 64);
    if ((tid & 63) == 0) wred[tid >> 6] = acc;
    __syncthreads();
    if (tid == 0) {
        float t = 0.f;
        #pragma unroll
        for (int k = 0; k < NTHR / 64; ++k) t += wred[k];
        atomicAdd(out, t * (-1.0f / (float)NVOX));
    }
}

extern "C" void kernel_launch(void* const* d_in, const int* in_sizes, int n_in,
                              void* d_out, int out_size, void* d_ws, size_t ws_size,
                              hipStream_t stream) {
    const float* I = (const float*)d_in[0];
    const float* J = (const float*)d_in[1];
    float* out = (float*)d_out;

    hipMemsetAsync(d_out, 0, sizeof(float), stream);  // harness re-poisons d_out

    dim3 blk(NTHR, 1, 1);
    dim3 grd(WW / TW, HH / TH, DD / DCH);             // 7 x 12 x 16 = 1344 blocks
    ncc_fused<<<grd, blk, 0, stream>>>(I, J, out);
}

// Round 5
// 140.595 us; speedup vs baseline: 4.6801x; 1.0555x over previous
//
#include <hip/hip_runtime.h>

// NCC loss, win=9, (1,1,160,192,224) fp32 -> scalar. Fully fused, round 5.
// Software-pipelined stages on disjoint wave groups, ONE barrier per slice:
//   stage1: waves 0-2 (192 thr): W(i+1) direct-global f4 loads, sliding 9-tap
//           W-sums -> SW[(i+1)&1] as b128 writes (row stride 36, 16B aligned)
//        || waves 3-5 (160 thr): H(i) column slide over SW[i&1] -> SH[i&1]
//   barrier
//   F(i): all 512 threads read SH[i&1] (5 b32), O(1) D-ring update, cc.
// Hazards: W(i+1)->H(i+1) RAW, H(i)->W(i+2) WAR, F(i)->H(i+2) WAR all cross
// the single barrier; double-buffered SW+SH covers the rest.
// Ring queue phase-static via 9-unrolled inner loop (18 iters = 2x9).

#define DD 160
#define HH 192
#define WW 224
#define W4 56                 // WW/4
#define SLICE (HH * WW)
#define S4 (SLICE / 4)
#define NVOX (DD * SLICE)
#define TW 32
#define TH 16
#define DCH 10                // grid.z = 16
#define NTHR 512
#define SW_RS 36              // mult of 4 -> b128-aligned rows; chan stride 864 % 32 == 0 -> 2-way (free)
#define SW_CS (24 * SW_RS)    // 864
#define SH_RS 33
#define SH_CS (TH * SH_RS)    // 528
#define EPS 1e-5f
#define INV_WSUM (1.0f / 729.0f)

__global__ __launch_bounds__(NTHR, 4) void ncc_fused(const float* __restrict__ I,
                                                     const float* __restrict__ J,
                                                     float* __restrict__ out) {
    __shared__ float SW0[5 * SW_CS], SW1[5 * SW_CS];   // 17.3 KB each
    __shared__ float SH0[5 * SH_CS], SH1[5 * SH_CS];   // 10.6 KB each
    __shared__ float wred[NTHR / 64];

    const int tid = threadIdx.x;
    const int tx = tid & 31, ty = tid >> 5;
    const int wlo = blockIdx.x * TW;
    const int hlo = blockIdx.y * TH;
    const int dlo = blockIdx.z * DCH;

    // W-group (tid < 192): 24 rows x 8 f4-cols
    const int wr = tid >> 3, wc = tid & 7;
    const int gh = hlo - 4 + wr;
    const bool hok = (gh >= 0) && (gh < HH);
    const int gf0 = (wlo >> 2) - 1 + wc;

    // H-group (tid in [192,352)): 5 channels x 32 cols
    const int ht = tid - 192;
    const int hcol = ht & 31, hch = ht >> 5;

    const float4* Iv = (const float4*)I;
    const float4* Jv = (const float4*)J;

    auto w_stage = [&](int z, float* dst) {
        const int rowb = z * S4 + gh * W4;
        float ax[12], bx[12];
        #pragma unroll
        for (int k = 0; k < 3; ++k) {
            const int f = gf0 + k;
            float4 a = make_float4(0.f, 0.f, 0.f, 0.f);
            float4 b = make_float4(0.f, 0.f, 0.f, 0.f);
            if (hok && f >= 0 && f < W4) { a = Iv[rowb + f]; b = Jv[rowb + f]; }
            ax[4*k] = a.x; ax[4*k+1] = a.y; ax[4*k+2] = a.z; ax[4*k+3] = a.w;
            bx[4*k] = b.x; bx[4*k+1] = b.y; bx[4*k+2] = b.z; bx[4*k+3] = b.w;
        }
        float* wp = dst + wr * SW_RS + 4 * wc;
        #pragma unroll
        for (int ch = 0; ch < 5; ++ch) {
            float v[12];
            #pragma unroll
            for (int k = 0; k < 12; ++k)
                v[k] = (ch == 0) ? ax[k]
                     : (ch == 1) ? bx[k]
                     : (ch == 2) ? ax[k] * ax[k]
                     : (ch == 3) ? bx[k] * bx[k]
                     :             ax[k] * bx[k];
            float s = v[0];
            #pragma unroll
            for (int k = 1; k < 9; ++k) s += v[k];
            float4 o;
            o.x = s;
            s += v[9]  - v[0]; o.y = s;
            s += v[10] - v[1]; o.z = s;
            s += v[11] - v[2]; o.w = s;
            *(float4*)(wp + ch * SW_CS) = o;   // b128, 16B-aligned (36*wr + 4*wc)
        }
    };

    float q0[9], q1[9], q2[9], q3[9], q4[9];
    #pragma unroll
    for (int k = 0; k < 9; ++k) { q0[k]=0.f; q1[k]=0.f; q2[k]=0.f; q3[k]=0.f; q4[k]=0.f; }
    float r0=0.f, r1=0.f, r2=0.f, r3=0.f, r4=0.f;
    float acc = 0.f;

    // prologue: stage z0 = dlo-4 into SW0
    {
        const int z0 = dlo - 4;
        if (tid < 192 && z0 >= 0) w_stage(z0, SW0);
    }
    __syncthreads();

    #pragma unroll 1
    for (int g = 0; g < 2; ++g) {
        #pragma unroll
        for (int ph = 0; ph < 9; ++ph) {
            const int i = g * 9 + ph;
            const int z = dlo - 4 + i;
            const bool val = (z >= 0) && (z < DD);        // block-uniform
            const int par = (g + ph) & 1;                 // == i & 1
            float* swR = par ? SW1 : SW0;
            float* swW = par ? SW0 : SW1;
            float* sh  = par ? SH1 : SH0;

            if (tid < 192) {
                const int zn = z + 1;
                if (i < DCH + 7 && zn >= 0 && zn < DD) w_stage(zn, swW);
            } else if (ht < 160 && val) {
                const float* p = swR + hch * SW_CS + hcol;
                float v[24];
                #pragma unroll
                for (int r = 0; r < 24; ++r) v[r] = p[r * SW_RS];
                float s = v[0];
                #pragma unroll
                for (int r = 1; r < 9; ++r) s += v[r];
                float* o = sh + hch * SH_CS + hcol;
                o[0] = s;
                #pragma unroll
                for (int r = 1; r < 16; ++r) {
                    s += v[r + 8] - v[r - 1];
                    o[r * SH_RS] = s;
                }
            }
            __syncthreads();

            float w0=0.f, w1=0.f, w2=0.f, w3=0.f, w4=0.f;
            if (val) {
                const float* p = sh + ty * SH_RS + tx;
                w0 = p[0];
                w1 = p[SH_CS];
                w2 = p[2 * SH_CS];
                w3 = p[3 * SH_CS];
                w4 = p[4 * SH_CS];
            }
            r0 += w0 - q0[ph]; q0[ph] = w0;
            r1 += w1 - q1[ph]; q1[ph] = w1;
            r2 += w2 - q2[ph]; q2[ph] = w2;
            r3 += w3 - q3[ph]; q3[ph] = w3;
            r4 += w4 - q4[ph]; q4[ph] = w4;

            if (i >= 8) {
                float cross = r4 - r0 * r1 * INV_WSUM;
                float iv    = r2 - r0 * r0 * INV_WSUM;
                float jv    = r3 - r1 * r1 * INV_WSUM;
                acc += cross * cross * __builtin_amdgcn_rcpf(iv * jv + EPS);
            }
        }
    }

    // ---- block reduction -> one atomic ----
    #pragma unroll
    for (int off = 32; off > 0; off >>= 1) acc += __shfl_down(acc, off, 64);
    if ((tid & 63) == 0) wred[tid >> 6] = acc;
    __syncthreads();
    if (tid == 0) {
        float t = 0.f;
        #pragma unroll
        for (int k = 0; k < NTHR / 64; ++k) t += wred[k];
        atomicAdd(out, t * (-1.0f / (float)NVOX));
    }
}

extern "C" void kernel_launch(void* const* d_in, const int* in_sizes, int n_in,
                              void* d_out, int out_size, void* d_ws, size_t ws_size,
                              hipStream_t stream) {
    const float* I = (const float*)d_in[0];
    const float* J = (const float*)d_in[1];
    float* out = (float*)d_out;

    hipMemsetAsync(d_out, 0, sizeof(float), stream);  // harness re-poisons d_out

    dim3 blk(NTHR, 1, 1);
    dim3 grd(WW / TW, HH / TH, DD / DCH);             // 7 x 12 x 16 = 1344 blocks
    ncc_fused<<<grd, blk, 0, stream>>>(I, J, out);
}